// Round 7
// baseline (401.919 us; speedup 1.0000x reference)
//
#include <hip/hip_runtime.h>

#define B_SZ 1024
#define H_SZ 2048
#define E_SZ 1024

typedef float  f32x4 __attribute__((ext_vector_type(4)));
typedef short  s16x8 __attribute__((ext_vector_type(8)));

__device__ __forceinline__ unsigned short f2bf(float f) {
    unsigned u = __float_as_uint(f);
    u = u + 0x7fffu + ((u >> 16) & 1u);   // RNE
    return (unsigned short)(u >> 16);
}
__device__ __forceinline__ float bf2f(unsigned short s) {
    return __uint_as_float(((unsigned)s) << 16);
}
__device__ __forceinline__ float sigm(float v) {
    return 1.0f / (1.0f + __expf(-v));
}

// ------------------------------------- swizzling cast (x, h only — 12 MB)
// fp32 [rows][K] -> bf16 MFMA A-fragment order (same layout as R6):
//   16B-unit t = ((nt*K32 + ks)*8 + half*4 + i)*64 + lane
//   row = nt*128 + half*64 + i*16 + (lane&15), k = ks*32 + (lane>>4)*8.
struct SwArgs {
    const float*    src[2];
    unsigned short* dst[2];
    int             log2K[2];
    int             nthr[2];
};

__global__ __launch_bounds__(256) void prep_kernel(SwArgs a) {
    const int arr = blockIdx.y;
    const int t = blockIdx.x * 256 + threadIdx.x;
    if (t >= a.nthr[arr]) return;
    const int lg   = a.log2K[arr];
    const int lane = t & 63;
    const int u    = t >> 6;
    const int hj   = u & 7;
    const int v    = u >> 3;
    const int k32m = (1 << (lg - 5)) - 1;
    const int ks   = v & k32m;
    const int nt   = v >> (lg - 5);
    const int row  = (nt << 7) + ((hj >> 2) << 6) + ((hj & 3) << 4) + (lane & 15);
    const int k    = (ks << 5) + ((lane >> 4) << 3);
    const float* s = a.src[arr] + ((size_t)row << lg) + k;
    float4 v0 = *(const float4*)s;
    float4 v1 = *(const float4*)(s + 4);
    s16x8 o;
    o[0] = (short)f2bf(v0.x); o[1] = (short)f2bf(v0.y);
    o[2] = (short)f2bf(v0.z); o[3] = (short)f2bf(v0.w);
    o[4] = (short)f2bf(v1.x); o[5] = (short)f2bf(v1.y);
    o[6] = (short)f2bf(v1.z); o[7] = (short)f2bf(v1.w);
    *(s16x8*)(a.dst[arr] + (size_t)t * 8) = o;
}

// A-fragment load from pre-swizzled bf16 (16 B/lane, fully coalesced)
#define LDF(dst, base, ks)                                                  \
    _Pragma("unroll") for (int _i = 0; _i < 4; ++_i)                        \
        dst[_i] = *(const s16x8*)((base) + (ks) * 4096 + _i * 512);

// Raw fp32 B-fragment load: frag j = rows +j*16, lane covers 8 consecutive k
#define LDBR(raw, bp, ks, Kc)                                               \
    _Pragma("unroll") for (int _j = 0; _j < 4; ++_j) {                      \
        const float* _p = (bp) + (size_t)(ks) * 32 + (size_t)_j * 16 * (Kc);\
        raw[2 * _j]     = *(const float4*)_p;                               \
        raw[2 * _j + 1] = *(const float4*)(_p + 4);                         \
    }

// fp32 -> bf16 truncation pack: one v_perm_b32 per 2 elements
#define PACKB(dst, raw)                                                     \
    _Pragma("unroll") for (int _j = 0; _j < 4; ++_j) {                      \
        uint4 _pk;                                                          \
        _pk.x = __builtin_amdgcn_perm(__float_as_uint(raw[2*_j].y),         \
                    __float_as_uint(raw[2*_j].x), 0x07060302u);             \
        _pk.y = __builtin_amdgcn_perm(__float_as_uint(raw[2*_j].w),         \
                    __float_as_uint(raw[2*_j].z), 0x07060302u);             \
        _pk.z = __builtin_amdgcn_perm(__float_as_uint(raw[2*_j+1].y),       \
                    __float_as_uint(raw[2*_j+1].x), 0x07060302u);           \
        _pk.w = __builtin_amdgcn_perm(__float_as_uint(raw[2*_j+1].w),       \
                    __float_as_uint(raw[2*_j+1].z), 0x07060302u);           \
        dst[_j] = __builtin_bit_cast(s16x8, _pk);                           \
    }

#define MF(aa, bb)                                                          \
    _Pragma("unroll") for (int _i = 0; _i < 4; ++_i)                        \
    _Pragma("unroll") for (int _j = 0; _j < 4; ++_j)                        \
        acc[_i][_j] = __builtin_amdgcn_mfma_f32_16x16x32_bf16(              \
            aa[_i], bb[_j], acc[_i][_j], 0, 0, 0);

// ---------------- gate GEMMs: LDS-free, fp32 weights read directly (no cast)
__global__ __launch_bounds__(256) void gates_kernel(
    const unsigned short* __restrict__ Xsw,
    const unsigned short* __restrict__ Hsw,
    const float* __restrict__ Wxi, const float* __restrict__ Wxg,
    const float* __restrict__ Wxf, const float* __restrict__ Wxo,
    const float* __restrict__ Whi, const float* __restrict__ Whg,
    const float* __restrict__ Whf, const float* __restrict__ Who,
    const float* __restrict__ bi, const float* __restrict__ bg,
    const float* __restrict__ bff, const float* __restrict__ bo,
    unsigned short* __restrict__ Z)
{
    const int t   = threadIdx.x;
    const int b   = blockIdx.x;
    const int xcd = b & 7;
    const int i_  = b >> 3;
    const int nt  = xcd * 8 + (i_ >> 3);    // 0..63 (q, n-tile)
    const int mt  = i_ & 7;
    const int q   = nt >> 4;
    const int n0t = nt & 15;
    const int lane = t & 63, w = t >> 6;
    const int hm = w >> 1, hn = w & 1;
    const int lr = lane & 15, kq = (lane >> 4) << 3;
    const int n0 = n0t * 128, wc = hn << 6;

    const unsigned short* ax = Xsw + (size_t)(mt * 256 + hm * 4) * 512 + lane * 8;
    const unsigned short* ah = Hsw + (size_t)(mt * 512 + hm * 4) * 512 + lane * 8;
    const float* Wxq = (q == 0) ? Wxi : (q == 1) ? Wxg : (q == 2) ? Wxf : Wxo;
    const float* Whq = (q == 0) ? Whi : (q == 1) ? Whg : (q == 2) ? Whf : Who;
    const float* bx = Wxq + (size_t)(n0 + wc + lr) * E_SZ + kq;
    const float* bh = Whq + (size_t)(n0 + wc + lr) * H_SZ + kq;

    f32x4 acc[4][4] = {};
    s16x8 a0[4], a1[4], bfrag[4];
    float4 r0[8], r1[8];

    LDF(a0, ax, 0); LDBR(r0, bx, 0, E_SZ);
    for (int ks = 0; ks < 30; ks += 2) {
        LDF(a1, ax, ks + 1); LDBR(r1, bx, ks + 1, E_SZ);
        PACKB(bfrag, r0); MF(a0, bfrag);
        LDF(a0, ax, ks + 2); LDBR(r0, bx, ks + 2, E_SZ);
        PACKB(bfrag, r1); MF(a1, bfrag);
    }
    LDF(a1, ax, 31); LDBR(r1, bx, 31, E_SZ);
    PACKB(bfrag, r0); MF(a0, bfrag);
    LDF(a0, ah, 0); LDBR(r0, bh, 0, H_SZ);      // transition into H-phase
    PACKB(bfrag, r1); MF(a1, bfrag);
    for (int ks = 0; ks < 62; ks += 2) {
        LDF(a1, ah, ks + 1); LDBR(r1, bh, ks + 1, H_SZ);
        PACKB(bfrag, r0); MF(a0, bfrag);
        LDF(a0, ah, ks + 2); LDBR(r0, bh, ks + 2, H_SZ);
        PACKB(bfrag, r1); MF(a1, bfrag);
    }
    LDF(a1, ah, 63); LDBR(r1, bh, 63, H_SZ);
    PACKB(bfrag, r0); MF(a0, bfrag);
    PACKB(bfrag, r1); MF(a1, bfrag);

    const float* bias = (q == 0) ? bi : (q == 1) ? bg : (q == 2) ? bff : bo;
    const int m0 = mt * 128;
    const int wr = hm << 6, rq = (lane >> 4) << 2;
    unsigned short* Zq = Z + (size_t)q * B_SZ * H_SZ;
#pragma unroll
    for (int i = 0; i < 4; ++i) {
#pragma unroll
        for (int j = 0; j < 4; ++j) {
            const int n = n0 + wc + j * 16 + lr;
            const float bv = bias[n];
#pragma unroll
            for (int r = 0; r < 4; ++r) {
                const int m = m0 + wr + i * 16 + rq + r;
                const float v = acc[i][j][r] + bv;
                const float a = (q == 1) ? tanhf(v) : sigm(v);
                Zq[(size_t)m * H_SZ + n] = f2bf(a);
            }
        }
    }
}

// ---------------- cell update; writes h_new fp32 + swizzled bf16 A-layout
__global__ __launch_bounds__(256) void cell_kernel(
    const unsigned short* __restrict__ Z, const float* __restrict__ c,
    float* __restrict__ c_out, float* __restrict__ h_out,
    unsigned short* __restrict__ Hnsw)
{
    const size_t BH = (size_t)B_SZ * H_SZ;
    const int t8 = blockIdx.x * 256 + threadIdx.x;
    const size_t base = (size_t)t8 * 8;

    s16x8 iu = *(const s16x8*)(Z + base);
    s16x8 gu = *(const s16x8*)(Z + BH + base);
    s16x8 fu = *(const s16x8*)(Z + 2 * BH + base);
    s16x8 ou = *(const s16x8*)(Z + 3 * BH + base);
    float4 c0 = *(const float4*)(c + base);
    float4 c1 = *(const float4*)(c + base + 4);
    const float cv[8] = {c0.x, c0.y, c0.z, c0.w, c1.x, c1.y, c1.z, c1.w};

    float cn[8], hn[8];
#pragma unroll
    for (int e = 0; e < 8; ++e) {
        cn[e] = bf2f((unsigned short)fu[e]) * cv[e]
              + bf2f((unsigned short)iu[e]) * bf2f((unsigned short)gu[e]);
        hn[e] = bf2f((unsigned short)ou[e]) * cn[e];
    }
    *(float4*)(c_out + base)     = make_float4(cn[0], cn[1], cn[2], cn[3]);
    *(float4*)(c_out + base + 4) = make_float4(cn[4], cn[5], cn[6], cn[7]);
    *(float4*)(h_out + base)     = make_float4(hn[0], hn[1], hn[2], hn[3]);
    *(float4*)(h_out + base + 4) = make_float4(hn[4], hn[5], hn[6], hn[7]);

    const int m  = (int)(base >> 11);
    const int hk = (int)(base & 2047);
    const int mt = m >> 7, half = (m >> 6) & 1, ii = (m >> 4) & 3, lr = m & 15;
    const int ks = hk >> 5, kq3 = (hk >> 3) & 3;
    const int lane2 = (kq3 << 4) | lr;
    const size_t toff = ((((size_t)mt * 64 + ks) * 8 + half * 4 + ii) * 64 + lane2) * 8;
    s16x8 hb;
#pragma unroll
    for (int e = 0; e < 8; ++e) hb[e] = (short)f2bf(hn[e]);
    *(s16x8*)(Hnsw + toff) = hb;
}

// ------------- y GEMM: LDS-free, split-K by 4, Why fp32 read directly
__global__ __launch_bounds__(256) void y_split_kernel(
    const unsigned short* __restrict__ Hnsw,
    const float* __restrict__ Wy,
    float* __restrict__ part)
{
    const int t   = threadIdx.x;
    const int b   = blockIdx.x;
    const int xcd = b & 7;
    const int i_  = b >> 3;
    const int ns  = xcd * 4 + (i_ >> 3);
    const int mt  = i_ & 7;
    const int n0t = ns >> 2;
    const int s   = ns & 3;
    const int lane = t & 63, w = t >> 6;
    const int hm = w >> 1, hn = w & 1;
    const int lr = lane & 15, kq = (lane >> 4) << 3;
    const int n0 = n0t * 128, wc = hn << 6;

    const unsigned short* ay = Hnsw
        + (size_t)((mt * 64 + s * 16) * 8 + hm * 4) * 512 + lane * 8;
    const float* bp = Wy + (size_t)(n0 + wc + lr) * H_SZ + s * 512 + kq;

    f32x4 acc[4][4] = {};
    s16x8 a0[4], a1[4], bfrag[4];
    float4 r0[8], r1[8];
    LDF(a0, ay, 0); LDBR(r0, bp, 0, H_SZ);
    for (int ks = 0; ks < 14; ks += 2) {
        LDF(a1, ay, ks + 1); LDBR(r1, bp, ks + 1, H_SZ);
        PACKB(bfrag, r0); MF(a0, bfrag);
        LDF(a0, ay, ks + 2); LDBR(r0, bp, ks + 2, H_SZ);
        PACKB(bfrag, r1); MF(a1, bfrag);
    }
    LDF(a1, ay, 15); LDBR(r1, bp, 15, H_SZ);
    PACKB(bfrag, r0); MF(a0, bfrag);
    PACKB(bfrag, r1); MF(a1, bfrag);

    const int m0 = mt * 128;
    const int wr = hm << 6, rq = (lane >> 4) << 2;
    float* P = part + (size_t)s * B_SZ * E_SZ;
#pragma unroll
    for (int i = 0; i < 4; ++i) {
#pragma unroll
        for (int j = 0; j < 4; ++j) {
            const int n = n0 + wc + j * 16 + lr;
#pragma unroll
            for (int r = 0; r < 4; ++r) {
                const int m = m0 + wr + i * 16 + rq + r;
                P[(size_t)m * E_SZ + n] = acc[i][j][r];
            }
        }
    }
}

__global__ __launch_bounds__(256) void y_reduce_kernel(
    const float* __restrict__ part, const float* __restrict__ by,
    float* __restrict__ yout)
{
    const size_t BE = (size_t)B_SZ * E_SZ;
    const int idx = (blockIdx.x * 256 + threadIdx.x) * 4;
    float4 a = *(const float4*)(part + idx);
    float4 b2 = *(const float4*)(part + BE + idx);
    float4 c2 = *(const float4*)(part + 2 * BE + idx);
    float4 d2 = *(const float4*)(part + 3 * BE + idx);
    const int col = idx & (E_SZ - 1);
    float4 bv = *(const float4*)(by + col);
    float4 o;
    o.x = tanhf(a.x + b2.x + c2.x + d2.x + bv.x);
    o.y = tanhf(a.y + b2.y + c2.y + d2.y + bv.y);
    o.z = tanhf(a.z + b2.z + c2.z + d2.z + bv.z);
    o.w = tanhf(a.w + b2.w + c2.w + d2.w + bv.w);
    *(float4*)(yout + idx) = o;
}

// ---------------------------------------------------------------- launch
extern "C" void kernel_launch(void* const* d_in, const int* in_sizes, int n_in,
                              void* d_out, int out_size, void* d_ws, size_t ws_size,
                              hipStream_t stream) {
    const float* x   = (const float*)d_in[0];
    const float* c   = (const float*)d_in[1];
    const float* h   = (const float*)d_in[2];
    const float* Wxi = (const float*)d_in[3];
    const float* Whi = (const float*)d_in[4];
    const float* Bi  = (const float*)d_in[5];
    const float* Wxg = (const float*)d_in[6];
    const float* Whg = (const float*)d_in[7];
    const float* Bg  = (const float*)d_in[8];
    const float* Wxf = (const float*)d_in[9];
    const float* Whf = (const float*)d_in[10];
    const float* Bf  = (const float*)d_in[11];
    const float* Wxo = (const float*)d_in[12];
    const float* Who = (const float*)d_in[13];
    const float* Bo  = (const float*)d_in[14];
    const float* Why = (const float*)d_in[15];
    const float* By  = (const float*)d_in[16];

    const size_t BE = (size_t)B_SZ * E_SZ, BH = (size_t)B_SZ * H_SZ;

    unsigned short* ws   = (unsigned short*)d_ws;
    unsigned short* Xsw  = ws;                 // BE bf16 (A-frag layout)
    unsigned short* Hsw  = Xsw + BE;           // BH
    unsigned short* Z    = Hsw + BH;           // 4*BH bf16; later fp32 y-partials
    unsigned short* Hnsw = Z + 4 * BH;         // BH

    SwArgs sa;
    sa.src[0] = x; sa.dst[0] = Xsw; sa.log2K[0] = 10; sa.nthr[0] = (int)(BE / 8);
    sa.src[1] = h; sa.dst[1] = Hsw; sa.log2K[1] = 11; sa.nthr[1] = (int)(BH / 8);

    hipLaunchKernelGGL(prep_kernel, dim3(1024, 2), dim3(256), 0, stream, sa);
    hipLaunchKernelGGL(gates_kernel, dim3(512), dim3(256), 0, stream,
                       Xsw, Hsw, Wxi, Wxg, Wxf, Wxo, Whi, Whg, Whf, Who,
                       Bi, Bg, Bf, Bo, Z);

    float* y_out = (float*)d_out;
    float* c_out = y_out + BE;
    float* h_out = c_out + BH;
    hipLaunchKernelGGL(cell_kernel, dim3((unsigned)(BH / 2048)), dim3(256), 0, stream,
                       Z, c, c_out, h_out, Hnsw);

    float* ypart = (float*)Z;   // Z dead after cell_kernel
    hipLaunchKernelGGL(y_split_kernel, dim3(256), dim3(256), 0, stream,
                       Hnsw, Why, ypart);
    hipLaunchKernelGGL(y_reduce_kernel, dim3((unsigned)(BE / 1024)), dim3(256), 0, stream,
                       ypart, By, y_out);
}

// Round 8
// 283.436 us; speedup vs baseline: 1.4180x; 1.4180x over previous
//
#include <hip/hip_runtime.h>

#define B_SZ 1024
#define H_SZ 2048
#define E_SZ 1024

typedef float  f32x4 __attribute__((ext_vector_type(4)));
typedef short  s16x8 __attribute__((ext_vector_type(8)));

__device__ __forceinline__ unsigned short f2bf(float f) {
    unsigned u = __float_as_uint(f);
    u = u + 0x7fffu + ((u >> 16) & 1u);   // RNE
    return (unsigned short)(u >> 16);
}
__device__ __forceinline__ float bf2f(unsigned short s) {
    return __uint_as_float(((unsigned)s) << 16);
}
__device__ __forceinline__ float sigm(float v) {
    return 1.0f / (1.0f + __expf(-v));
}
__device__ __forceinline__ void gll(const unsigned short* g, unsigned short* l) {
    __builtin_amdgcn_global_load_lds(
        (const __attribute__((address_space(1))) unsigned int*)g,
        (__attribute__((address_space(3))) unsigned int*)l, 16, 0, 0);
}

// --------------------------------- cast pass (x, h only — 12 MB fp32 in)
struct CastArgs {
    const float*    src[2];
    unsigned short* dst[2];
    int             n[2];
};

__global__ __launch_bounds__(256) void cast_kernel(CastArgs a) {
    const int arr = blockIdx.y;
    const int n = a.n[arr];
    const float* __restrict__ s = a.src[arr];
    unsigned short* __restrict__ d = a.dst[arr];
    const int stride = gridDim.x * 256 * 4;
    for (int i = (blockIdx.x * 256 + threadIdx.x) * 4; i < n; i += stride) {
        float4 v = *(const float4*)(s + i);
        ushort4 o;
        o.x = f2bf(v.x); o.y = f2bf(v.y); o.z = f2bf(v.z); o.w = f2bf(v.w);
        *(ushort4*)(d + i) = o;
    }
}

// ---------------- GEMM core: bf16 A via global_load_lds, fp32 W staged
// through registers (coalesced row-major loads) -> truncate-pack bf16 ->
// ds_write_b128 into the SAME XOR-swizzled 128x64 LDS layout as R5
// (slot col-block = cb ^ (row&7)), so fragment reads stay conflict-free.
// acc += A[128 @ m0][kLen]_bf16 @ W[128 @ n0][kLen]_fp32^T.
__device__ __forceinline__ void gemm_f32w(
    const unsigned short* __restrict__ A,
    const float* __restrict__ W,
    int ldA, int ldB, int kLen, int m0, int n0,
    unsigned short* lA, unsigned short* lB,
    f32x4 acc[4][4], int t)
{
    const int lane = t & 63;
    const int w    = t >> 6;
    const int wr   = (w >> 1) << 6;
    const int wc   = (w & 1) << 6;
    const int lr   = lane & 15;
    const int q4   = lane >> 4;

    const int srow = t >> 3;                       // 0..31
    const int swc8 = (t & 7) ^ (srow & 7);         // swizzled col-block
    const int scol = swc8 << 3;
    const unsigned short* gA = A + (size_t)(m0 + srow) * ldA + scol;
    const float*          gB = W + (size_t)(n0 + srow) * ldB + ((t & 7) << 3);
    const size_t stA = (size_t)32 * ldA;
    const size_t stB = (size_t)32 * ldB;
    // LDS dest for B chunks: row srow+32p, col-block swc8 (since 32p%8==0)
    unsigned short* lBw = lB + srow * 64 + scol;

    const int cb0 = ((q4    ) ^ (lr & 7)) << 3;
    const int cb1 = ((4 + q4) ^ (lr & 7)) << 3;

    for (int k0 = 0; k0 < kLen; k0 += 64) {
        // A: async direct-to-LDS (swizzled source col)
#pragma unroll
        for (int p = 0; p < 4; ++p)
            gll(gA + k0 + p * stA, lA + (t + 256 * p) * 8);
        // B: fp32 coalesced -> pack -> LDS
        float4 f0[4], f1[4];
#pragma unroll
        for (int p = 0; p < 4; ++p) {
            const float* s = gB + k0 + p * stB;
            f0[p] = *(const float4*)s;
            f1[p] = *(const float4*)(s + 4);
        }
#pragma unroll
        for (int p = 0; p < 4; ++p) {
            uint4 pk;
            pk.x = __builtin_amdgcn_perm(__float_as_uint(f0[p].y),
                        __float_as_uint(f0[p].x), 0x07060302u);
            pk.y = __builtin_amdgcn_perm(__float_as_uint(f0[p].w),
                        __float_as_uint(f0[p].z), 0x07060302u);
            pk.z = __builtin_amdgcn_perm(__float_as_uint(f1[p].y),
                        __float_as_uint(f1[p].x), 0x07060302u);
            pk.w = __builtin_amdgcn_perm(__float_as_uint(f1[p].w),
                        __float_as_uint(f1[p].z), 0x07060302u);
            *(uint4*)(lBw + p * 32 * 64) = pk;
        }
        __syncthreads();

#pragma unroll
        for (int ks = 0; ks < 2; ++ks) {
            const int cb = ks ? cb1 : cb0;
            s16x8 af[4], bfr[4];
#pragma unroll
            for (int i = 0; i < 4; ++i)
                af[i] = *(const s16x8*)(lA + (wr + i * 16 + lr) * 64 + cb);
#pragma unroll
            for (int j = 0; j < 4; ++j)
                bfr[j] = *(const s16x8*)(lB + (wc + j * 16 + lr) * 64 + cb);
#pragma unroll
            for (int i = 0; i < 4; ++i)
#pragma unroll
                for (int j = 0; j < 4; ++j)
                    acc[i][j] = __builtin_amdgcn_mfma_f32_16x16x32_bf16(
                        af[i], bfr[j], acc[i][j], 0, 0, 0);
        }
        __syncthreads();
    }
}

// -------------------------------------------------------------- gate GEMMs
// 512 blocks, XCD swizzle as R2/R5. Weights read fp32 directly from d_in.
__global__ __launch_bounds__(256) void gates_kernel(
    const unsigned short* __restrict__ Xb,
    const unsigned short* __restrict__ Hb,
    const float* __restrict__ Wxi, const float* __restrict__ Wxg,
    const float* __restrict__ Wxf, const float* __restrict__ Wxo,
    const float* __restrict__ Whi, const float* __restrict__ Whg,
    const float* __restrict__ Whf, const float* __restrict__ Who,
    const float* __restrict__ bi, const float* __restrict__ bg,
    const float* __restrict__ bff, const float* __restrict__ bo,
    unsigned short* __restrict__ Z)
{
    __shared__ unsigned short lA[128 * 64];
    __shared__ unsigned short lB[128 * 64];
    const int t   = threadIdx.x;
    const int b   = blockIdx.x;
    const int xcd = b & 7;
    const int i_  = b >> 3;
    const int nt  = xcd * 8 + (i_ >> 3);    // 0..63 (q, n-tile)
    const int m0  = (i_ & 7) * 128;
    const int q   = nt >> 4;
    const int n0  = (nt & 15) * 128;

    const float* Wxq = (q == 0) ? Wxi : (q == 1) ? Wxg : (q == 2) ? Wxf : Wxo;
    const float* Whq = (q == 0) ? Whi : (q == 1) ? Whg : (q == 2) ? Whf : Who;

    f32x4 acc[4][4] = {};
    gemm_f32w(Xb, Wxq, E_SZ, E_SZ, E_SZ, m0, n0, lA, lB, acc, t);
    gemm_f32w(Hb, Whq, H_SZ, H_SZ, H_SZ, m0, n0, lA, lB, acc, t);

    const float* bias = (q == 0) ? bi : (q == 1) ? bg : (q == 2) ? bff : bo;
    const int lane = t & 63, w = t >> 6;
    const int wr = (w >> 1) << 6, wc = (w & 1) << 6;
    const int lr = lane & 15, rq = (lane >> 4) << 2;
    unsigned short* Zq = Z + (size_t)q * B_SZ * H_SZ;
#pragma unroll
    for (int i = 0; i < 4; ++i) {
#pragma unroll
        for (int j = 0; j < 4; ++j) {
            const int n = n0 + wc + j * 16 + lr;
            const float bv = bias[n];
#pragma unroll
            for (int r = 0; r < 4; ++r) {
                const int m = m0 + wr + i * 16 + rq + r;
                const float v = acc[i][j][r] + bv;
                const float a = (q == 1) ? tanhf(v) : sigm(v);
                Zq[(size_t)m * H_SZ + n] = f2bf(a);
            }
        }
    }
}

// ------------------------------------------------------------ cell update
__global__ __launch_bounds__(256) void cell_kernel(
    const unsigned short* __restrict__ Z, const float* __restrict__ c,
    float* __restrict__ c_out, float* __restrict__ h_out,
    unsigned short* __restrict__ HnB)
{
    const size_t BH = (size_t)B_SZ * H_SZ;
    const int idx = (blockIdx.x * 256 + threadIdx.x) * 4;
    ushort4 iu = *(const ushort4*)(Z + idx);
    ushort4 gu = *(const ushort4*)(Z + BH + idx);
    ushort4 fu = *(const ushort4*)(Z + 2 * BH + idx);
    ushort4 ou = *(const ushort4*)(Z + 3 * BH + idx);
    float4 cv = *(const float4*)(c + idx);

    float cn[4], hn[4];
    cn[0] = bf2f(fu.x) * cv.x + bf2f(iu.x) * bf2f(gu.x);
    cn[1] = bf2f(fu.y) * cv.y + bf2f(iu.y) * bf2f(gu.y);
    cn[2] = bf2f(fu.z) * cv.z + bf2f(iu.z) * bf2f(gu.z);
    cn[3] = bf2f(fu.w) * cv.w + bf2f(iu.w) * bf2f(gu.w);
    hn[0] = bf2f(ou.x) * cn[0];
    hn[1] = bf2f(ou.y) * cn[1];
    hn[2] = bf2f(ou.z) * cn[2];
    hn[3] = bf2f(ou.w) * cn[3];

    *(float4*)(c_out + idx) = make_float4(cn[0], cn[1], cn[2], cn[3]);
    *(float4*)(h_out + idx) = make_float4(hn[0], hn[1], hn[2], hn[3]);
    ushort4 hb;
    hb.x = f2bf(hn[0]); hb.y = f2bf(hn[1]); hb.z = f2bf(hn[2]); hb.w = f2bf(hn[3]);
    *(ushort4*)(HnB + idx) = hb;
}

// ---------------------- y GEMM, split-K by 4, Why fp32 staged via LDS
__global__ __launch_bounds__(256) void y_split_kernel(
    const unsigned short* __restrict__ Hn,
    const float* __restrict__ Wy,
    float* __restrict__ part)
{
    __shared__ unsigned short lA[128 * 64];
    __shared__ unsigned short lB[128 * 64];
    const int t   = threadIdx.x;
    const int b   = blockIdx.x;
    const int xcd = b & 7;
    const int i_  = b >> 3;
    const int ns  = xcd * 4 + (i_ >> 3);
    const int m0  = (i_ & 7) * 128;
    const int n0  = (ns >> 2) * 128;
    const int s   = ns & 3;

    f32x4 acc[4][4] = {};
    gemm_f32w(Hn + s * 512, Wy + s * 512, H_SZ, H_SZ, 512, m0, n0, lA, lB, acc, t);

    const int lane = t & 63, w = t >> 6;
    const int wr = (w >> 1) << 6, wc = (w & 1) << 6;
    const int lr = lane & 15, rq = (lane >> 4) << 2;
    float* P = part + (size_t)s * B_SZ * E_SZ;
#pragma unroll
    for (int i = 0; i < 4; ++i) {
#pragma unroll
        for (int j = 0; j < 4; ++j) {
            const int n = n0 + wc + j * 16 + lr;
#pragma unroll
            for (int r = 0; r < 4; ++r) {
                const int m = m0 + wr + i * 16 + rq + r;
                P[(size_t)m * E_SZ + n] = acc[i][j][r];
            }
        }
    }
}

__global__ __launch_bounds__(256) void y_reduce_kernel(
    const float* __restrict__ part, const float* __restrict__ by,
    float* __restrict__ yout)
{
    const size_t BE = (size_t)B_SZ * E_SZ;
    const int idx = (blockIdx.x * 256 + threadIdx.x) * 4;
    float4 a = *(const float4*)(part + idx);
    float4 b2 = *(const float4*)(part + BE + idx);
    float4 c2 = *(const float4*)(part + 2 * BE + idx);
    float4 d2 = *(const float4*)(part + 3 * BE + idx);
    const int col = idx & (E_SZ - 1);
    float4 bv = *(const float4*)(by + col);
    float4 o;
    o.x = tanhf(a.x + b2.x + c2.x + d2.x + bv.x);
    o.y = tanhf(a.y + b2.y + c2.y + d2.y + bv.y);
    o.z = tanhf(a.z + b2.z + c2.z + d2.z + bv.z);
    o.w = tanhf(a.w + b2.w + c2.w + d2.w + bv.w);
    *(float4*)(yout + idx) = o;
}

// ---------------------------------------------------------------- launch
extern "C" void kernel_launch(void* const* d_in, const int* in_sizes, int n_in,
                              void* d_out, int out_size, void* d_ws, size_t ws_size,
                              hipStream_t stream) {
    const float* x   = (const float*)d_in[0];
    const float* c   = (const float*)d_in[1];
    const float* h   = (const float*)d_in[2];
    const float* Wxi = (const float*)d_in[3];
    const float* Whi = (const float*)d_in[4];
    const float* Bi  = (const float*)d_in[5];
    const float* Wxg = (const float*)d_in[6];
    const float* Whg = (const float*)d_in[7];
    const float* Bg  = (const float*)d_in[8];
    const float* Wxf = (const float*)d_in[9];
    const float* Whf = (const float*)d_in[10];
    const float* Bf  = (const float*)d_in[11];
    const float* Wxo = (const float*)d_in[12];
    const float* Who = (const float*)d_in[13];
    const float* Bo  = (const float*)d_in[14];
    const float* Why = (const float*)d_in[15];
    const float* By  = (const float*)d_in[16];

    const size_t BE = (size_t)B_SZ * E_SZ, BH = (size_t)B_SZ * H_SZ;

    unsigned short* ws  = (unsigned short*)d_ws;
    unsigned short* Xb  = ws;                 // BE bf16
    unsigned short* Hb  = Xb + BE;            // BH
    unsigned short* Z   = Hb + BH;            // 4*BH bf16; later fp32 y-partials
    unsigned short* HnB = Z + 4 * BH;         // BH

    CastArgs ca;
    ca.src[0] = x; ca.dst[0] = Xb; ca.n[0] = (int)BE;
    ca.src[1] = h; ca.dst[1] = Hb; ca.n[1] = (int)BH;

    hipLaunchKernelGGL(cast_kernel, dim3(1024, 2), dim3(256), 0, stream, ca);
    hipLaunchKernelGGL(gates_kernel, dim3(512), dim3(256), 0, stream,
                       Xb, Hb, Wxi, Wxg, Wxf, Wxo, Whi, Whg, Whf, Who,
                       Bi, Bg, Bf, Bo, Z);

    float* y_out = (float*)d_out;
    float* c_out = y_out + BE;
    float* h_out = c_out + BH;
    hipLaunchKernelGGL(cell_kernel, dim3((unsigned)(BH / 1024)), dim3(256), 0, stream,
                       Z, c, c_out, h_out, HnB);

    float* ypart = (float*)Z;   // Z dead after cell_kernel
    hipLaunchKernelGGL(y_split_kernel, dim3(256), dim3(256), 0, stream,
                       HnB, Why, ypart);
    hipLaunchKernelGGL(y_reduce_kernel, dim3((unsigned)(BE / 1024)), dim3(256), 0, stream,
                       ypart, By, y_out);
}